// Round 7
// baseline (1537.082 us; speedup 1.0000x reference)
//
#include <hip/hip_runtime.h>
#include <math.h>

#define BB 64
#define TT 2048
#define FF 128
#define HH 32
#define GG 128  // 4*H
#define NC 4    // chains (batch elements) per wave

// gate-column prescale: sigma(a) = rcp(1 + exp2(S1*a)), tanh(a) = 2*rcp(1+exp2(S2*a))-1
#define S1f (-1.4426950408889634f)  // -log2(e)
#define S2f (-2.8853900817779268f)  // -2*log2(e)

typedef _Float16 half2_t __attribute__((ext_vector_type(2)));

__device__ __forceinline__ unsigned h2u(half2_t v) {
    unsigned u; __builtin_memcpy(&u, &v, 4); return u;
}
__device__ __forceinline__ half2_t u2h(unsigned u) {
    half2_t v; __builtin_memcpy(&v, &u, 4); return v;
}
__device__ __forceinline__ half2_t pkrtz(float a, float b) {
    auto r = __builtin_amdgcn_cvt_pkrtz(a, b);  // __fp16 vec2, same bits
    half2_t v; __builtin_memcpy(&v, &r, 4); return v;
}
__device__ __forceinline__ float rcp_(float x) { return __builtin_amdgcn_rcpf(x); }
__device__ __forceinline__ float exp2_(float x) { return __builtin_amdgcn_exp2f(x); }

// DPP lane shuffles (within rows of 16 / quads); bound_ctrl=1, all rows/banks
#define DPP_(x, ctrl) \
    ((unsigned)__builtin_amdgcn_mov_dpp((int)(x), (ctrl), 0xF, 0xF, true))
#define CTRL_XOR1 0xB1  // quad_perm [1,0,3,2]
#define CTRL_XOR2 0x4E  // quad_perm [2,3,0,1]
#define CTRL_ROR4 0x124 // row_ror:4
#define CTRL_ROR8 0x128 // row_ror:8
// ds_swizzle bit-mode xor16 within 32-lane groups: (16<<10)|0x1F
#define SWZ16_(x) ((unsigned)__builtin_amdgcn_ds_swizzle((int)(x), 0x401F))

// ---------------- Kernel 1: xg'[b][col][t] = scale[col]*(X[b,t,:]@Wx + b)[col]
__global__ __launch_bounds__(256) void xg_gemm(const float* __restrict__ X,
                                               const float* __restrict__ Wx,
                                               const float* __restrict__ bias,
                                               float* __restrict__ xgT) {
    __shared__ float XL[64 * 32];    // [row][fi]  8 KB
    __shared__ float WL[32 * 128];   // [fi][col] 16 KB
    const int tid = threadIdx.x;
    const int row0 = blockIdx.x * 64;   // flattened b*T + t0 (one b per block)
    const int j0 = (tid & 15) * 8;   // 8 output cols
    const int r0 = (tid >> 4) * 4;   // 4 output rows (consecutive t)

    float acc[4][8];
#pragma unroll
    for (int r = 0; r < 4; ++r)
#pragma unroll
        for (int jj = 0; jj < 8; ++jj) acc[r][jj] = 0.f;

    for (int f0 = 0; f0 < FF; f0 += 32) {
        __syncthreads();
        {
            const float4* src = (const float4*)(Wx + f0 * GG);
            float4* dst = (float4*)WL;
            dst[tid]       = src[tid];
            dst[tid + 256] = src[tid + 256];
            dst[tid + 512] = src[tid + 512];
            dst[tid + 768] = src[tid + 768];
        }
        {
            int lin = tid * 4;
            int row = lin >> 5;
            int fi  = lin & 31;
            ((float4*)XL)[tid] =
                *(const float4*)(X + (size_t)(row0 + row) * FF + f0 + fi);
            lin = (tid + 256) * 4;
            row = lin >> 5;
            fi  = lin & 31;
            ((float4*)XL)[tid + 256] =
                *(const float4*)(X + (size_t)(row0 + row) * FF + f0 + fi);
        }
        __syncthreads();
#pragma unroll 4
        for (int fi = 0; fi < 32; ++fi) {
            float xv[4];
#pragma unroll
            for (int r = 0; r < 4; ++r) xv[r] = XL[(r0 + r) * 32 + fi];
            float4 w0 = *(float4*)&WL[fi * GG + j0];
            float4 w1 = *(float4*)&WL[fi * GG + j0 + 4];
            float w[8] = {w0.x, w0.y, w0.z, w0.w, w1.x, w1.y, w1.z, w1.w};
#pragma unroll
            for (int r = 0; r < 4; ++r)
#pragma unroll
                for (int jj = 0; jj < 8; ++jj)
                    acc[r][jj] = fmaf(xv[r], w[jj], acc[r][jj]);
        }
    }
    const int b  = row0 >> 11;            // row0 / 2048
    const int t0 = (row0 & 2047) + r0;
    float bl[8];
#pragma unroll
    for (int jj = 0; jj < 8; ++jj) bl[jj] = bias[j0 + jj];
#pragma unroll
    for (int jj = 0; jj < 8; ++jj) {
        const int j = j0 + jj;
        const float sc = (j >= 64 && j < 96) ? S2f : S1f;
        float4 o;
        o.x = (acc[0][jj] + bl[jj]) * sc;
        o.y = (acc[1][jj] + bl[jj]) * sc;
        o.z = (acc[2][jj] + bl[jj]) * sc;
        o.w = (acc[3][jj] + bl[jj]) * sc;
        *(float4*)(xgT + ((size_t)b * GG + j) * TT + t0) = o;
    }
}

// ---------------- Kernel 2: LSTM scan, butterfly h-gather, NC chains/wave --
// One wave per block; block handles NC batch elements (independent chains
// interleaved to fill dependency stalls; Wh registers shared). Lane l owns
// gate columns l and l+64; per chain, lane l holds h[l&31], c[l&31].
__global__ __launch_bounds__(64) void lstm_rec(const float* __restrict__ xgT,
                                               const float* __restrict__ Wh,
                                               const float* __restrict__ Wd,
                                               const float* __restrict__ bd,
                                               float* __restrict__ out) {
    const int l = threadIdx.x;  // 0..63
    const int m = l & 31;
    const bool lo = (l < HH);
    const int b0 = blockIdx.x * NC;

    // ---- discover gather permutation: run the tree on the index ----
    unsigned iv[16];
    iv[0] = (unsigned)m;
    iv[1] = SWZ16_(iv[0]);
    iv[2] = DPP_(iv[0], CTRL_XOR2);
    iv[3] = DPP_(iv[1], CTRL_XOR2);
#pragma unroll
    for (int r = 0; r < 4; ++r) iv[4 + r] = DPP_(iv[r], CTRL_ROR4);
#pragma unroll
    for (int r = 0; r < 8; ++r) iv[8 + r] = DPP_(iv[r], CTRL_ROR8);

    // ---- load Wh columns l and l+64, permuted + prescaled + fp16-packed ---
    const float scx = S1f;                 // col l: i (lo) or f (hi) -> sigmoid
    const float scy = lo ? S2f : S1f;      // col l+64: g (lo, tanh) or o (hi)
    half2_t whx[16], why[16];
#pragma unroll
    for (int r = 0; r < 16; ++r) {
        const int p  = (int)(iv[r] & 31u);
        const int p2 = p ^ 1;
        whx[r] = pkrtz(Wh[p * GG + l] * scx,       Wh[p2 * GG + l] * scx);
        why[r] = pkrtz(Wh[p * GG + l + 64] * scy,  Wh[p2 * GG + l + 64] * scy);
    }

    // per-lane affine for act1: tanh = 2*s-1 (lo), sigmoid = s (hi)
    const float A1 = lo ? 2.f : 1.f;
    const float B1 = lo ? -1.f : 0.f;

    float h[NC], c[NC];
    const float* pX[NC];
    const float* pY[NC];
    float4 curX[NC], curY[NC], nxtX[NC], nxtY[NC];
#pragma unroll
    for (int q = 0; q < NC; ++q) {
        h[q] = 0.f; c[q] = 0.f;
        pX[q] = xgT + ((size_t)(b0 + q) * GG + l) * TT;
        pY[q] = xgT + ((size_t)(b0 + q) * GG + l + 64) * TT;
        curX[q] = *(const float4*)(pX[q]);
        curY[q] = *(const float4*)(pY[q]);
        nxtX[q] = *(const float4*)(pX[q] + 4);
        nxtY[q] = *(const float4*)(pY[q] + 4);
    }

    auto step = [&](float& hq, float& cq, float xi, float xy)
        __attribute__((always_inline)) {
        // ---- butterfly all-gather: h (1 f32/lane) -> 16 packed half2 ----
        unsigned g[16];
        unsigned hn = DPP_(__float_as_uint(hq), CTRL_XOR1);  // h[m^1]
        g[0] = h2u(pkrtz(hq, __uint_as_float(hn)));          // (h[m], h[m^1])
        g[1] = SWZ16_(g[0]);
        g[2] = DPP_(g[0], CTRL_XOR2);
        g[3] = DPP_(g[1], CTRL_XOR2);
#pragma unroll
        for (int r = 0; r < 4; ++r) g[4 + r] = DPP_(g[r], CTRL_ROR4);
#pragma unroll
        for (int r = 0; r < 8; ++r) g[8 + r] = DPP_(g[r], CTRL_ROR8);

        // ---- matvec: 32 all-VGPR fdot2, 4-way split accumulators ----
        float ax[4] = {xi, 0.f, 0.f, 0.f};
        float ay[4] = {xy, 0.f, 0.f, 0.f};
#pragma unroll
        for (int r = 0; r < 16; ++r) {
            half2_t hp = u2h(g[r]);
            ax[r & 3] = __builtin_amdgcn_fdot2(hp, whx[r], ax[r & 3], false);
            ay[r & 3] = __builtin_amdgcn_fdot2(hp, why[r], ay[r & 3], false);
        }
        float a0 = (ax[0] + ax[1]) + (ax[2] + ax[3]);  // prescaled, col l
        float a1 = (ay[0] + ay[1]) + (ay[2] + ay[3]);  // prescaled, col l+64

        // act0 = sigmoid (i|f); act1 = tanh (g) on lo, sigmoid (o) on hi
        float act0 = rcp_(1.f + exp2_(a0));
        float act1 = fmaf(A1, rcp_(1.f + exp2_(a1)), B1);

        // two independent half-swaps: p={i|g} q={f|o} u={g|i} v={o|f}
        auto pq = __builtin_amdgcn_permlane32_swap(__float_as_uint(act0),
                                                   __float_as_uint(act1), false, false);
        auto uv = __builtin_amdgcn_permlane32_swap(__float_as_uint(act1),
                                                   __float_as_uint(act0), false, false);
        float p = __uint_as_float(pq[0]);
        float q = __uint_as_float(pq[1]);
        float u = __uint_as_float(uv[0]);
        float v = __uint_as_float(uv[1]);

        float f_all = lo ? q : act0;   // sigmoid(f)
        float o_all = lo ? v : act1;   // sigmoid(o)
        cq = fmaf(f_all, cq, u * p);   // u*p = i*g in every lane
        float tc = fmaf(2.f, rcp_(1.f + exp2_(cq * S2f)), -1.f);  // tanh(c)
        hq = o_all * tc;
    };

#pragma unroll 1
    for (int t4 = 0; t4 < TT; t4 += 4) {
        float4 uX[NC], uY[NC];
#pragma unroll
        for (int q = 0; q < NC; ++q) {
            uX[q] = curX[q]; uY[q] = curY[q];
            curX[q] = nxtX[q]; curY[q] = nxtY[q];
        }
        if (t4 + 8 < TT) {
#pragma unroll
            for (int q = 0; q < NC; ++q) {
                nxtX[q] = *(const float4*)(pX[q] + t4 + 8);
                nxtY[q] = *(const float4*)(pY[q] + t4 + 8);
            }
        }
#pragma unroll
        for (int q = 0; q < NC; ++q) step(h[q], c[q], uX[q].x, uY[q].x);
#pragma unroll
        for (int q = 0; q < NC; ++q) step(h[q], c[q], uX[q].y, uY[q].y);
#pragma unroll
        for (int q = 0; q < NC; ++q) step(h[q], c[q], uX[q].z, uY[q].z);
#pragma unroll
        for (int q = 0; q < NC; ++q) step(h[q], c[q], uX[q].w, uY[q].w);
    }

    // out[b] = h_T @ Wd + bd   (each h[k] appears twice across 64 lanes)
    const float wd = Wd[m];
#pragma unroll
    for (int q = 0; q < NC; ++q) {
        float contrib = h[q] * wd;
#pragma unroll
        for (int off = 32; off >= 1; off >>= 1)
            contrib += __shfl_xor(contrib, off, 64);
        if (l == 0) out[b0 + q] = fmaf(0.5f, contrib, bd[0]);
    }
}

extern "C" void kernel_launch(void* const* d_in, const int* in_sizes, int n_in,
                              void* d_out, int out_size, void* d_ws, size_t ws_size,
                              hipStream_t stream) {
    const float* X    = (const float*)d_in[0];
    const float* Wx   = (const float*)d_in[1];
    const float* Wh   = (const float*)d_in[2];
    const float* bias = (const float*)d_in[3];
    const float* Wd   = (const float*)d_in[4];
    const float* bd   = (const float*)d_in[5];
    float* out = (float*)d_out;
    float* xgT = (float*)d_ws;  // [64][128][2048] floats = 64 MB

    hipLaunchKernelGGL(xg_gemm, dim3((BB * TT) / 64), dim3(256), 0, stream,
                       X, Wx, bias, xgT);
    hipLaunchKernelGGL(lstm_rec, dim3(BB / NC), dim3(64), 0, stream,
                       xgT, Wh, Wd, bd, out);
}

// Round 8
// 500.196 us; speedup vs baseline: 3.0730x; 3.0730x over previous
//
#include <hip/hip_runtime.h>
#include <math.h>

#define BB 64
#define TT 2048
#define FF 128
#define HH 32
#define GG 128  // 4*H

// gate-column prescale: sigma(a) = rcp(1 + exp2(S1*a)), tanh(a) = 2*rcp(1+exp2(S2*a))-1
#define S1f (-1.4426950408889634f)  // -log2(e)
#define S2f (-2.8853900817779268f)  // -2*log2(e)

typedef _Float16 half2_t __attribute__((ext_vector_type(2)));

__device__ __forceinline__ unsigned h2u(half2_t v) {
    unsigned u; __builtin_memcpy(&u, &v, 4); return u;
}
__device__ __forceinline__ half2_t u2h(unsigned u) {
    half2_t v; __builtin_memcpy(&v, &u, 4); return v;
}
__device__ __forceinline__ half2_t pkrtz(float a, float b) {
    auto r = __builtin_amdgcn_cvt_pkrtz(a, b);  // __fp16 vec2, same bits
    half2_t v; __builtin_memcpy(&v, &r, 4); return v;
}
__device__ __forceinline__ float rcp_(float x) { return __builtin_amdgcn_rcpf(x); }
__device__ __forceinline__ float exp2_(float x) { return __builtin_amdgcn_exp2f(x); }

// DPP lane shuffles (within rows of 16 / quads); bound_ctrl=1, all rows/banks
#define DPP_(x, ctrl) \
    ((unsigned)__builtin_amdgcn_mov_dpp((int)(x), (ctrl), 0xF, 0xF, true))
#define CTRL_XOR1 0xB1  // quad_perm [1,0,3,2]
#define CTRL_XOR2 0x4E  // quad_perm [2,3,0,1]
#define CTRL_ROR4 0x124 // row_ror:4
#define CTRL_ROR8 0x128 // row_ror:8
// ds_swizzle bit-mode xor16 within 32-lane groups: (16<<10)|0x1F
#define SWZ16_(x) ((unsigned)__builtin_amdgcn_ds_swizzle((int)(x), 0x401F))

#if __has_builtin(__builtin_amdgcn_permlane16_swap)
#define HAVE_PL16 1
#else
#define HAVE_PL16 0
#endif

// Build the 16-reg all-gather tree from seed reg v0 (packed pair or index).
// Pure VALU when permlane16_swap exists; ds_swizzle fallback otherwise.
// The same tree is run on indices at setup (discovery) and on h each step,
// so only the permutation's *fixedness* matters, not its exact semantics.
__device__ __forceinline__ void gather_tree(unsigned v0, unsigned g[16]) {
    unsigned v1 = DPP_(v0, CTRL_XOR2);
#if HAVE_PL16
    auto sw = __builtin_amdgcn_permlane16_swap(v0, v1, false, false);
    unsigned s0 = (unsigned)sw[0], s1 = (unsigned)sw[1];
    g[0] = s0;
    g[1] = s1;
    g[2] = DPP_(s0, CTRL_XOR2);
    g[3] = DPP_(s1, CTRL_XOR2);
#else
    g[0] = v0;
    g[1] = v1;
    g[2] = SWZ16_(v0);
    g[3] = SWZ16_(v1);
#endif
#pragma unroll
    for (int r = 0; r < 4; ++r) g[4 + r] = DPP_(g[r], CTRL_ROR4);
#pragma unroll
    for (int r = 0; r < 8; ++r) g[8 + r] = DPP_(g[r], CTRL_ROR8);
}

// ---------------- Kernel 1: xg'[b][col][t] = scale[col]*(X[b,t,:]@Wx + b)[col]
__global__ __launch_bounds__(256) void xg_gemm(const float* __restrict__ X,
                                               const float* __restrict__ Wx,
                                               const float* __restrict__ bias,
                                               float* __restrict__ xgT) {
    __shared__ float XL[64 * 32];    // [row][fi]  8 KB
    __shared__ float WL[32 * 128];   // [fi][col] 16 KB
    const int tid = threadIdx.x;
    const int row0 = blockIdx.x * 64;   // flattened b*T + t0 (one b per block)
    const int j0 = (tid & 15) * 8;   // 8 output cols
    const int r0 = (tid >> 4) * 4;   // 4 output rows (consecutive t)

    float acc[4][8];
#pragma unroll
    for (int r = 0; r < 4; ++r)
#pragma unroll
        for (int jj = 0; jj < 8; ++jj) acc[r][jj] = 0.f;

    for (int f0 = 0; f0 < FF; f0 += 32) {
        __syncthreads();
        {
            const float4* src = (const float4*)(Wx + f0 * GG);
            float4* dst = (float4*)WL;
            dst[tid]       = src[tid];
            dst[tid + 256] = src[tid + 256];
            dst[tid + 512] = src[tid + 512];
            dst[tid + 768] = src[tid + 768];
        }
        {
            int lin = tid * 4;
            int row = lin >> 5;
            int fi  = lin & 31;
            ((float4*)XL)[tid] =
                *(const float4*)(X + (size_t)(row0 + row) * FF + f0 + fi);
            lin = (tid + 256) * 4;
            row = lin >> 5;
            fi  = lin & 31;
            ((float4*)XL)[tid + 256] =
                *(const float4*)(X + (size_t)(row0 + row) * FF + f0 + fi);
        }
        __syncthreads();
#pragma unroll 4
        for (int fi = 0; fi < 32; ++fi) {
            float xv[4];
#pragma unroll
            for (int r = 0; r < 4; ++r) xv[r] = XL[(r0 + r) * 32 + fi];
            float4 w0 = *(float4*)&WL[fi * GG + j0];
            float4 w1 = *(float4*)&WL[fi * GG + j0 + 4];
            float w[8] = {w0.x, w0.y, w0.z, w0.w, w1.x, w1.y, w1.z, w1.w};
#pragma unroll
            for (int r = 0; r < 4; ++r)
#pragma unroll
                for (int jj = 0; jj < 8; ++jj)
                    acc[r][jj] = fmaf(xv[r], w[jj], acc[r][jj]);
        }
    }
    const int b  = row0 >> 11;            // row0 / 2048
    const int t0 = (row0 & 2047) + r0;
    float bl[8];
#pragma unroll
    for (int jj = 0; jj < 8; ++jj) bl[jj] = bias[j0 + jj];
#pragma unroll
    for (int jj = 0; jj < 8; ++jj) {
        const int j = j0 + jj;
        const float sc = (j >= 64 && j < 96) ? S2f : S1f;
        float4 o;
        o.x = (acc[0][jj] + bl[jj]) * sc;
        o.y = (acc[1][jj] + bl[jj]) * sc;
        o.z = (acc[2][jj] + bl[jj]) * sc;
        o.w = (acc[3][jj] + bl[jj]) * sc;
        *(float4*)(xgT + ((size_t)b * GG + j) * TT + t0) = o;
    }
}

// ---------------- Kernel 2: single-wave LSTM scan, all-VALU h-gather -------
// One block (one wave) per batch element. Lane l owns gate columns l and
// l+64; lane l holds h[l&31], c[l&31] (both 32-lane halves redundant).
// h is broadcast each step by an all-VALU butterfly (DPP + permlane16_swap)
// into 16 packed-fp16 VGPRs; Wh is pre-permuted per lane at setup by running
// the identical shuffle tree on the index, so the matvec is 32 all-VGPR
// v_dot2_f32_f16 with no DS/SGPR traffic on the critical path.
__global__ __launch_bounds__(64) void lstm_rec(const float* __restrict__ xgT,
                                               const float* __restrict__ Wh,
                                               const float* __restrict__ Wd,
                                               const float* __restrict__ bd,
                                               float* __restrict__ out) {
    const int l = threadIdx.x;  // 0..63
    const int m = l & 31;
    const bool lo = (l < HH);
    const int b = blockIdx.x;

    // ---- discover gather permutation: run the tree on the index ----
    unsigned iv[16];
    gather_tree((unsigned)m, iv);

    // ---- load Wh columns l and l+64, permuted + prescaled + fp16-packed ---
    const float scx = S1f;                 // col l: i (lo) or f (hi) -> sigmoid
    const float scy = lo ? S2f : S1f;      // col l+64: g (lo, tanh) or o (hi)
    half2_t whx[16], why[16];
#pragma unroll
    for (int r = 0; r < 16; ++r) {
        const int p  = (int)(iv[r] & 31u);
        const int p2 = p ^ 1;
        whx[r] = pkrtz(Wh[p * GG + l] * scx,       Wh[p2 * GG + l] * scx);
        why[r] = pkrtz(Wh[p * GG + l + 64] * scy,  Wh[p2 * GG + l + 64] * scy);
    }

    // per-lane affine for act1: tanh = 2*s-1 (lo), sigmoid = s (hi)
    const float A1 = lo ? 2.f : 1.f;
    const float B1 = lo ? -1.f : 0.f;

    float h = 0.f;  // lane l: h[m]
    float c = 0.f;  // lane l: c[m]

    const float* pX = xgT + ((size_t)b * GG + l) * TT;        // col l
    const float* pY = xgT + ((size_t)b * GG + l + 64) * TT;   // col l+64

    float4 curX = *(const float4*)(pX);
    float4 curY = *(const float4*)(pY);
    float4 nxtX = *(const float4*)(pX + 4);
    float4 nxtY = *(const float4*)(pY + 4);

    auto step = [&](float xi, float xy) __attribute__((always_inline)) {
        // ---- all-VALU butterfly gather: h (1 f32/lane) -> 16 packed half2 -
        unsigned hn = DPP_(__float_as_uint(h), CTRL_XOR1);   // h[m^1]
        unsigned g0 = h2u(pkrtz(h, __uint_as_float(hn)));    // (h[m], h[m^1])
        unsigned g[16];
        gather_tree(g0, g);

        // ---- matvec: 32 all-VGPR fdot2, 4-way split accumulators ----
        float ax[4] = {xi, 0.f, 0.f, 0.f};
        float ay[4] = {xy, 0.f, 0.f, 0.f};
#pragma unroll
        for (int r = 0; r < 16; ++r) {
            half2_t hp = u2h(g[r]);
            ax[r & 3] = __builtin_amdgcn_fdot2(hp, whx[r], ax[r & 3], false);
            ay[r & 3] = __builtin_amdgcn_fdot2(hp, why[r], ay[r & 3], false);
        }
        float a0 = (ax[0] + ax[1]) + (ax[2] + ax[3]);  // prescaled, col l
        float a1 = (ay[0] + ay[1]) + (ay[2] + ay[3]);  // prescaled, col l+64

        // act0 = sigmoid (i|f); act1 = tanh (g) on lo, sigmoid (o) on hi
        float act0 = rcp_(1.f + exp2_(a0));
        float act1 = fmaf(A1, rcp_(1.f + exp2_(a1)), B1);

        // two independent half-swaps: p={i|g} q={f|o} u={g|i} v={o|f}
        auto pq = __builtin_amdgcn_permlane32_swap(__float_as_uint(act0),
                                                   __float_as_uint(act1), false, false);
        auto uv = __builtin_amdgcn_permlane32_swap(__float_as_uint(act1),
                                                   __float_as_uint(act0), false, false);
        float p = __uint_as_float(pq[0]);
        float q = __uint_as_float(pq[1]);
        float u = __uint_as_float(uv[0]);
        float v = __uint_as_float(uv[1]);

        float f_all = lo ? q : act0;   // sigmoid(f)
        float o_all = lo ? v : act1;   // sigmoid(o)
        c = fmaf(f_all, c, u * p);     // u*p = i*g in every lane
        float tc = fmaf(2.f, rcp_(1.f + exp2_(c * S2f)), -1.f);  // tanh(c)
        h = o_all * tc;
    };

#pragma unroll 1
    for (int t4 = 0; t4 < TT; t4 += 4) {
        float4 uX = curX, uY = curY;
        curX = nxtX; curY = nxtY;
        if (t4 + 8 < TT) {
            nxtX = *(const float4*)(pX + t4 + 8);
            nxtY = *(const float4*)(pY + t4 + 8);
        }
        step(uX.x, uY.x);
        step(uX.y, uY.y);
        step(uX.z, uY.z);
        step(uX.w, uY.w);
    }

    // out[b] = h_T @ Wd + bd   (each h[k] appears twice across 64 lanes)
    float contrib = h * Wd[m];
#pragma unroll
    for (int off = 32; off >= 1; off >>= 1)
        contrib += __shfl_xor(contrib, off, 64);
    if (l == 0) out[b] = fmaf(0.5f, contrib, bd[0]);
}

extern "C" void kernel_launch(void* const* d_in, const int* in_sizes, int n_in,
                              void* d_out, int out_size, void* d_ws, size_t ws_size,
                              hipStream_t stream) {
    const float* X    = (const float*)d_in[0];
    const float* Wx   = (const float*)d_in[1];
    const float* Wh   = (const float*)d_in[2];
    const float* bias = (const float*)d_in[3];
    const float* Wd   = (const float*)d_in[4];
    const float* bd   = (const float*)d_in[5];
    float* out = (float*)d_out;
    float* xgT = (float*)d_ws;  // [64][128][2048] floats = 64 MB

    hipLaunchKernelGGL(xg_gemm, dim3((BB * TT) / 64), dim3(256), 0, stream,
                       X, Wx, bias, xgT);
    hipLaunchKernelGGL(lstm_rec, dim3(BB), dim3(64), 0, stream,
                       xgT, Wh, Wd, bd, out);
}